// Round 13
// baseline (357.705 us; speedup 1.0000x reference)
//
#include <hip/hip_runtime.h>
#include <hip/hip_bf16.h>
#include <math.h>

typedef __hip_bfloat16 bf16;
typedef unsigned short ushort_t;

__device__ __forceinline__ float us2f(ushort_t u){
  union { unsigned u; float f; } v; v.u = ((unsigned)u) << 16; return v.f;
}
// native RNE f32->bf16
__device__ __forceinline__ ushort_t f2us(float f){
  union { __bf16 b; ushort_t u; } v; v.b = (__bf16)f; return v.u;
}

// tanh-form GELU == x * sigmoid(2c(x + 0.044715 x^3)); branch-free, NaN-free.
__device__ __forceinline__ float gelu_f(float x){
  float y = x * fmaf(0.0356774081f, x*x, 0.7978845608f);
  float e = __expf(-2.0f*y);
  return x * __builtin_amdgcn_rcpf(1.0f + e);
}

#define B_ 16
#define T_ 24
#define N_ 512
#define D_ 64
#define F_ 256

typedef __attribute__((ext_vector_type(8)))  short  frag8;
typedef __attribute__((ext_vector_type(16))) float  accv16;

__device__ __forceinline__ float wave_sum(float v){
#pragma unroll
  for (int off = 32; off > 0; off >>= 1) v += __shfl_xor(v, off, 64);
  return v;
}

// ---------- degree^-1/2 ----------
__global__ __launch_bounds__(64) void k_dinv(const float* __restrict__ adj,
                                             float* __restrict__ dinv){
  int m = blockIdx.x;
  float s = 0.f;
  for (int n = threadIdx.x; n < N_; n += 64) s += adj[m*N_ + n];
  s = wave_sum(s);
  if (threadIdx.x == 0){
    float deg = s + 1.0f;
    dinv[m] = rsqrtf(fmaxf(deg, 1e-12f));
  }
}

// ---------- Ahat (bf16) + AhatT ----------
__global__ __launch_bounds__(256) void k_ahat(const float* __restrict__ adj,
                                              const float* __restrict__ dinv,
                                              ushort_t* __restrict__ AhatB,
                                              ushort_t* __restrict__ AhatBT){
  int idx = blockIdx.x*256 + threadIdx.x;
  int m = idx >> 9, n = idx & (N_-1);
  float a = adj[idx] + (m == n ? 1.f : 0.f);
  ushort_t v = f2us(dinv[m]*a*dinv[n]);
  AhatB[idx] = v;
  AhatBT[n*N_ + m] = v;
}

// ---------- Ahat^2 = Ahat @ Ahat ----------
__global__ __launch_bounds__(256, 4) void k_ah2(
    const ushort_t* __restrict__ A1,
    const ushort_t* __restrict__ A1T,
    ushort_t* __restrict__ A2)
{
  __shared__ __align__(16) ushort_t Ab[64][72];
  __shared__ __align__(16) ushort_t Bb[64][72];
  __shared__ __align__(16) ushort_t Yt[64][72];
  int tid  = threadIdx.x;
  int lane = tid & 63, w = tid >> 6;
  int mw = (w >> 1) * 32, nw = (w & 1) * 32;
  int l31 = lane & 31, lh = lane >> 5;
  int m0 = blockIdx.x * 64, n0 = blockIdx.y * 64;
  int ar = tid >> 3, ac8 = (tid & 7) * 8;

  accv16 acc = {};
  for (int k0 = 0; k0 < N_; k0 += 64){
#pragma unroll
    for (int g = 0; g < 2; g++){
      int rr = ar + g*32;
      *(uint4*)&Ab[rr][ac8] = *(const uint4*)&A1 [(size_t)(m0 + rr)*N_ + k0 + ac8];
      *(uint4*)&Bb[rr][ac8] = *(const uint4*)&A1T[(size_t)(n0 + rr)*N_ + k0 + ac8];
    }
    __syncthreads();
#pragma unroll
    for (int kk = 0; kk < 64; kk += 16){
      frag8 af = *(const frag8*)&Ab[mw + l31][kk + lh*8];
      frag8 bf = *(const frag8*)&Bb[nw + l31][kk + lh*8];
      acc = __builtin_amdgcn_mfma_f32_32x32x16_bf16(af, bf, acc, 0, 0, 0);
    }
    __syncthreads();
  }
#pragma unroll
  for (int r = 0; r < 16; r++){
    int row = mw + (r & 3) + 8*(r >> 2) + 4*lh;
    Yt[row][nw + l31] = f2us(acc[r]);
  }
  __syncthreads();
#pragma unroll
  for (int g = 0; g < 2; g++){
    int rr = ar + g*32;
    *(uint4*)&A2[(size_t)(m0 + rr)*N_ + n0 + ac8] = *(const uint4*)&Yt[rr][ac8];
  }
}

// ---------- pre-transpose weights to bf16 B-operand layout [dout][e] ----------
__global__ __launch_bounds__(256) void k_wprep(
    const float* __restrict__ W1, const float* __restrict__ W2,
    const float* __restrict__ Wq, const float* __restrict__ Wk,
    const float* __restrict__ Wv, const float* __restrict__ Wo,
    const float* __restrict__ gcW,
    ushort_t* __restrict__ W1t, ushort_t* __restrict__ W2t,
    ushort_t* __restrict__ Wqt, ushort_t* __restrict__ Wkt,
    ushort_t* __restrict__ Wvt, ushort_t* __restrict__ Wot,
    ushort_t* __restrict__ gWt){
  int o = blockIdx.x*256 + threadIdx.x;   // 0..16383
  int f = o >> 6, e = o & 63;
  W1t[o] = f2us(W1[e*256 + f]);
  int d = o >> 8, e2 = o & 255;
  W2t[o] = f2us(W2[e2*64 + d]);
  if (o < 4096){
    int dd = o >> 6, ee = o & 63;
    Wqt[o] = f2us(Wq[ee*64 + dd]);
    Wkt[o] = f2us(Wk[ee*64 + dd]);
    Wvt[o] = f2us(Wv[ee*64 + dd]);
    Wot[o] = f2us(Wo[ee*64 + dd]);
    gWt[o]        = f2us(gcW[       ee*64 + dd]);   // k=0
    gWt[4096 + o] = f2us(gcW[4096 + ee*64 + dd]);   // k=1
    gWt[8192 + o] = f2us(gcW[8192 + ee*64 + dd]);   // k=2
  }
}

// ---------- attention: 2 nodes (48 tokens) per block (r10, unchanged) ----------
__global__ __launch_bounds__(256, 4) void k_attn_m(
    const float* __restrict__ x,
    const ushort_t* __restrict__ Wqt, const float* __restrict__ bq,
    const ushort_t* __restrict__ Wkt, const float* __restrict__ bk,
    const ushort_t* __restrict__ Wvt, const float* __restrict__ bv,
    const ushort_t* __restrict__ Wot, const float* __restrict__ bo,
    const float* __restrict__ g_t, const float* __restrict__ b_t,
    float* __restrict__ h1)
{
  __shared__ __align__(16) char smem[28928];
  ushort_t (*xsA)[72] = (ushort_t(*)[72]) smem;                 // [48][72]
  ushort_t (*qs)[72]  = (ushort_t(*)[72])(smem + 6912);         // [48][72]
  ushort_t (*ks)[72]  = (ushort_t(*)[72])(smem + 13824);        // [48][72]
  float    (*Os)[68]  = (float(*)[68])   (smem + 6912);         // [48][68] alias (13056B)
  ushort_t *vsT       = (ushort_t*)(smem + 20736);              // [128][32], swizzled

  int tid = threadIdx.x;
  int lane = tid & 63, w = tid >> 6;
  int l31 = lane & 31, lh = lane >> 5;
  int mt = (w >> 1) * 32, nt = (w & 1) * 32;
  int b = blockIdx.x >> 8;
  int n0 = (blockIdx.x & 255) * 2;

  {
    uint4 z4 = {0,0,0,0};
#pragma unroll
    for (int i = 0; i < 2; i++)
      *(uint4*)(smem + 20736 + (tid + i*256)*16) = z4;
  }
#pragma unroll
  for (int i = 0; i < 3; i++){
    int idx = tid + i*256;
    int row = idx >> 4, d4 = (idx & 15) * 4;
    int node = row >= 24;
    int t = row - node*24;
    const float4 v = *(const float4*)&x[(((size_t)b*T_ + t)*N_ + n0 + node)*D_ + d4];
    ushort_t tmp[4] = { f2us(v.x), f2us(v.y), f2us(v.z), f2us(v.w) };
    *(unsigned long long*)&xsA[row][d4] = *(unsigned long long*)tmp;
  }
  __syncthreads();

#pragma unroll
  for (int pj = 0; pj < 3; pj++){
    const ushort_t* Wp = (pj==0 ? Wqt : pj==1 ? Wkt : Wvt);
    accv16 a = {};
#pragma unroll
    for (int kk = 0; kk < 64; kk += 16){
      frag8 af = *(const frag8*)&xsA[mt + l31][kk + lh*8];
      frag8 bf = *(const frag8*)&Wp[(size_t)(nt + l31)*64 + kk + lh*8];
      a = __builtin_amdgcn_mfma_f32_32x32x16_bf16(af, bf, a, 0, 0, 0);
    }
    float bias = (pj==0 ? bq : pj==1 ? bk : bv)[nt + l31];
    if (pj < 2){
      ushort_t (*dst)[72] = (pj==0 ? qs : ks);
#pragma unroll
      for (int r = 0; r < 16; r++){
        int row = mt + (r & 3) + 8*(r >> 2) + 4*lh;
        if (row < 48) dst[row][nt + l31] = f2us(a[r] + bias);
      }
    } else {
      int cl = nt + l31;                  // 0..63 = head*16 + d_local
#pragma unroll
      for (int r = 0; r < 16; r++){
        int row = mt + (r & 3) + 8*(r >> 2) + 4*lh;
        if (row < 48){
          int node = (row >= 24);
          int t2 = row - node*24;
          int Rr = node*64 + cl;
          vsT[Rr*32 + (((t2 >> 3) ^ ((Rr >> 1) & 3)) << 3) + (t2 & 7)] = f2us(a[r] + bias);
        }
      }
    }
  }
  __syncthreads();

  int vs_s = (l31 >> 1) & 3;
#pragma unroll
  for (int gi = 0; gi < 2; gi++){
    int g = w*2 + gi;
    int node = g >> 2, hh = g & 3;
    accv16 s = {};
    frag8 kf = *(const frag8*)&ks[node*24 + l31][hh*16 + lh*8];
    frag8 qf = *(const frag8*)&qs[node*24 + l31][hh*16 + lh*8];
    s = __builtin_amdgcn_mfma_f32_32x32x16_bf16(kf, qf, s, 0, 0, 0);
    float e[12]; float sm = 0.f;
#pragma unroll
    for (int r = 0; r < 12; r++){ e[r] = __expf(s[r]*0.25f); sm += e[r]; }
    sm += __shfl_xor(sm, 32, 64);
    float rinv = 1.0f / sm;
    union { unsigned long long q; ushort_t u[4]; } a0, a1, a2;
#pragma unroll
    for (int j = 0; j < 4; j++){
      a0.u[j] = f2us(e[j]   * rinv);
      a1.u[j] = f2us(e[4+j] * rinv);
      a2.u[j] = f2us(e[8+j] * rinv);
    }
    unsigned long long send1 = lh ? a0.q : a1.q;
    unsigned long long r1 = __shfl_xor(send1, 32, 64);
    unsigned long long r2 = __shfl_xor(a2.q, 32, 64);
    union { frag8 f; unsigned long long q[2]; } f0, f1;
    f0.q[0] = lh ? r1   : a0.q;
    f0.q[1] = lh ? a1.q : r1;
    f1.q[0] = lh ? 0ULL : a2.q;
    f1.q[1] = lh ? 0ULL : r2;
    int vrow = node*64 + hh*16 + (l31 & 15);
    const ushort_t* vb = &vsT[vrow*32];
    frag8 bf0 = *(const frag8*)&vb[((0 + lh) ^ vs_s) << 3];
    frag8 bf1 = *(const frag8*)&vb[((2 + lh) ^ vs_s) << 3];
    accv16 acc = {};
    acc = __builtin_amdgcn_mfma_f32_32x32x16_bf16(f0.f, bf0, acc, 0, 0, 0);
    acc = __builtin_amdgcn_mfma_f32_32x32x16_bf16(f1.f, bf1, acc, 0, 0, 0);
    if (l31 < 16){
#pragma unroll
      for (int r = 0; r < 12; r++){
        int row = (r & 3) + 8*(r >> 2) + 4*lh;
        xsA[node*24 + row][hh*16 + l31] = f2us(acc[r]);
      }
    }
  }
  __syncthreads();

  accv16 ao = {};
#pragma unroll
  for (int kk = 0; kk < 64; kk += 16){
    frag8 af = *(const frag8*)&xsA[mt + l31][kk + lh*8];
    frag8 bf = *(const frag8*)&Wot[(size_t)(nt + l31)*64 + kk + lh*8];
    ao = __builtin_amdgcn_mfma_f32_32x32x16_bf16(af, bf, ao, 0, 0, 0);
  }
  {
    float bov = bo[nt + l31];
#pragma unroll
    for (int r = 0; r < 16; r++){
      int row = mt + (r & 3) + 8*(r >> 2) + 4*lh;
      if (row < 48) Os[row][nt + l31] = ao[r] + bov;
    }
  }
  __syncthreads();

  // ---- LN tail: 4 lanes per row, fp32 x re-read, float4 I/O ----
  {
    int rrow = tid >> 2, seg = (tid & 3) * 16;
    if (rrow < 48){
      int node = rrow >= 24;
      int t = rrow - node*24;
      size_t gbase = (((size_t)b*T_ + t)*N_ + n0 + node)*D_;
      float vb[16]; float s1 = 0.f;
#pragma unroll
      for (int j4 = 0; j4 < 4; j4++){
        float4 xo = *(const float4*)&x[gbase + seg + j4*4];
        float4 ov = *(const float4*)&Os[rrow][seg + j4*4];
        vb[j4*4+0] = ov.x + xo.x;
        vb[j4*4+1] = ov.y + xo.y;
        vb[j4*4+2] = ov.z + xo.z;
        vb[j4*4+3] = ov.w + xo.w;
        s1 += vb[j4*4+0] + vb[j4*4+1] + vb[j4*4+2] + vb[j4*4+3];
      }
      s1 += __shfl_xor(s1, 1, 64); s1 += __shfl_xor(s1, 2, 64);
      float m = s1 * (1.f/64.f);
      float s2 = 0.f;
#pragma unroll
      for (int j = 0; j < 16; j++){ vb[j] -= m; s2 += vb[j]*vb[j]; }
      s2 += __shfl_xor(s2, 1, 64); s2 += __shfl_xor(s2, 2, 64);
      float rstd = rsqrtf(s2 * (1.f/64.f) + 1e-5f);
#pragma unroll
      for (int j4 = 0; j4 < 4; j4++){
        float4 gv = *(const float4*)&g_t[seg + j4*4];
        float4 bv = *(const float4*)&b_t[seg + j4*4];
        float4 st;
        st.x = vb[j4*4+0]*rstd*gv.x + bv.x;
        st.y = vb[j4*4+1]*rstd*gv.y + bv.y;
        st.z = vb[j4*4+2]*rstd*gv.z + bv.z;
        st.w = vb[j4*4+3]*rstd*gv.w + bv.w;
        *(float4*)&h1[gbase + seg + j4*4] = st;
      }
    }
  }
}

// ---------- hT = transpose(h) per (b,t) slice ----------
__global__ __launch_bounds__(256, 8) void k_hT(const float* __restrict__ h,
                                               ushort_t* __restrict__ hT){
  __shared__ __align__(16) ushort_t tb[64][76];
  int tid = threadIdx.x;
  int n0 = (blockIdx.x & 7) * 64;
  size_t bt = blockIdx.x >> 3;
  const float* src = h + (bt*N_ + n0)*D_;
#pragma unroll
  for (int i = 0; i < 4; i++){
    int q = tid + i*256;
    int row = q >> 4, d4 = (q & 15)*4;
    float4 v = *(const float4*)&src[(size_t)q*4];
    ushort_t tmp[4] = { f2us(v.x), f2us(v.y), f2us(v.z), f2us(v.w) };
    *(unsigned long long*)&tb[row][d4] = *(unsigned long long*)tmp;
  }
  __syncthreads();
  int d = tid >> 2, nseg = (tid & 3)*16;
  ushort_t tmp[16];
#pragma unroll
  for (int j = 0; j < 16; j++){
    int jj = (j + ((d & 7) << 1)) & 15;
    tmp[jj] = tb[nseg + jj][d];
  }
  ushort_t* dst = hT + (bt*D_ + d)*N_ + n0 + nseg;
  *(uint4*)&dst[0] = *(uint4*)&tmp[0];
  *(uint4*)&dst[8] = *(uint4*)&tmp[8];
}

// ---------- fused gconv + comb + FFN: 512 threads, 128-row m-tile ----------
// r13: r10's proven patterns (BK=64, 8-thread/row uint4 staging, [.][72]
// strides) scaled to 8 waves sharing the A/X tiles. Per-thread registers
// unchanged (no spill); 2 blocks x 8 waves = 16 waves/CU; 1536 blocks ->
// 3 residency generations (vs r10's 4). LDS 55296B (2 blocks/CU).
__global__ __launch_bounds__(512, 4) void k_gcffn(
    const ushort_t* __restrict__ A1,
    const ushort_t* __restrict__ A2,
    const ushort_t* __restrict__ XT,
    const ushort_t* __restrict__ gWt,   // [3][64][64] bf16 B-layout
    const float* __restrict__ gcb,
    const float* __restrict__ g_g, const float* __restrict__ b_g,
    const ushort_t* __restrict__ W1t, const ushort_t* __restrict__ W2t,
    const float* __restrict__ b1, const float* __restrict__ b2,
    const float* __restrict__ g_f, const float* __restrict__ b_f,
    float* __restrict__ h)
{
  __shared__ __align__(16) char smem[55296];
  ushort_t (*R0)[72] = (ushort_t(*)[72]) smem;             // [128][72] A1 / Y2
  ushort_t (*R1)[72] = (ushort_t(*)[72])(smem + 18432);    // [128][72] A2 / Y1
  ushort_t (*RX)[72] = (ushort_t(*)[72])(smem + 36864);    // [64][72] X ; [128][72] h1/h2
  float    (*Sf)[68]  = (float(*)[68])    smem;            // [128][68] f32 (34816)
  ushort_t (*Uc)[136] = (ushort_t(*)[136])smem;            // [128][136] (34816)
  float    (*Os)[68]  = (float(*)[68])    smem;

  int tid = threadIdx.x;
  int lane = tid & 63, w = tid >> 6;        // w in 0..7
  int l31 = lane & 31, lh = lane >> 5;
  int mw = (w & 3) * 32, nw = (w >> 2) * 32;
  // XCD decode: x=bid&7 pins XCD; m-tile=(bid>>3)&3; slice=(bid>>5)*8+x
  int bid = blockIdx.x;
  int m0 = ((bid >> 3) & 3) * 128;
  size_t bt = (size_t)((bid >> 5) * 8 + (bid & 7));
  const ushort_t* Xg = XT + bt * (N_ * D_);
  size_t tokbase = bt * N_ + m0;
  int ar = tid >> 3, ac8 = (tid & 7) * 8;   // ar 0..63, ac8 0..56

  // ---- P1: dual-hop K-loop (BK=64, A tiles 128 rows shared by 8 waves) ----
  accv16 acc1 = {}, acc2 = {};
  for (int k0 = 0; k0 < N_; k0 += 64){
#pragma unroll
    for (int g = 0; g < 2; g++){
      int rr = ar + g*64;
      *(uint4*)&R0[rr][ac8] = *(const uint4*)&A1[(size_t)(m0 + rr)*N_ + k0 + ac8];
      *(uint4*)&R1[rr][ac8] = *(const uint4*)&A2[(size_t)(m0 + rr)*N_ + k0 + ac8];
    }
    *(uint4*)&RX[ar][ac8] = *(const uint4*)&Xg[(size_t)ar*N_ + k0 + ac8];
    __syncthreads();
#pragma unroll
    for (int kk = 0; kk < 64; kk += 16){
      frag8 bf  = *(const frag8*)&RX[nw + l31][kk + lh*8];
      frag8 af1 = *(const frag8*)&R0[mw + l31][kk + lh*8];
      frag8 af2 = *(const frag8*)&R1[mw + l31][kk + lh*8];
      acc1 = __builtin_amdgcn_mfma_f32_32x32x16_bf16(af1, bf, acc1, 0, 0, 0);
      acc2 = __builtin_amdgcn_mfma_f32_32x32x16_bf16(af2, bf, acc2, 0, 0, 0);
    }
    __syncthreads();
  }

  // ---- P2: Y writes + h1 tile stage (128 rows); 3-term g-sum ----
#pragma unroll
  for (int r = 0; r < 16; r++){
    int row = mw + (r & 3) + 8*(r >> 2) + 4*lh;
    R1[row][nw + l31] = f2us(acc1[r]);   // Y1
    R0[row][nw + l31] = f2us(acc2[r]);   // Y2
  }
#pragma unroll
  for (int i = 0; i < 4; i++){
    int q = tid + i*512;                 // float4 idx over 128x64 tile
    int row = q >> 4, d4 = (q & 15) * 4;
    float4 v = *(const float4*)&h[tokbase*64 + (size_t)q*4];
    ushort_t tmp[4] = { f2us(v.x), f2us(v.y), f2us(v.z), f2us(v.w) };
    *(unsigned long long*)&RX[row][d4] = *(unsigned long long*)tmp;
  }
  __syncthreads();                       // B_a

  accv16 ag = {};
#pragma unroll
  for (int kk = 0; kk < 64; kk += 16){
    frag8 a0f = *(const frag8*)&RX[mw + l31][kk + lh*8];
    frag8 b0f = *(const frag8*)&gWt[(size_t)(nw + l31)*64 + kk + lh*8];
    ag = __builtin_amdgcn_mfma_f32_32x32x16_bf16(a0f, b0f, ag, 0, 0, 0);
  }
#pragma unroll
  for (int kk = 0; kk < 64; kk += 16){
    frag8 a1f = *(const frag8*)&R1[mw + l31][kk + lh*8];
    frag8 b1f = *(const frag8*)&gWt[4096 + (size_t)(nw + l31)*64 + kk + lh*8];
    ag = __builtin_amdgcn_mfma_f32_32x32x16_bf16(a1f, b1f, ag, 0, 0, 0);
  }
#pragma unroll
  for (int kk = 0; kk < 64; kk += 16){
    frag8 a2f = *(const frag8*)&R0[mw + l31][kk + lh*8];
    frag8 b2f = *(const frag8*)&gWt[8192 + (size_t)(nw + l31)*64 + kk + lh*8];
    ag = __builtin_amdgcn_mfma_f32_32x32x16_bf16(a2f, b2f, ag, 0, 0, 0);
  }
  __syncthreads();                       // B_b: drain R0/R1/RX reads

  // ---- P3: S = ag + h1(fp32) + bias -> Sf [128][68]; mid-LN ----
  {
    int col = nw + l31;
    float bs = gcb[col] + gcb[64 + col] + gcb[128 + col];
#pragma unroll
    for (int r = 0; r < 16; r++){
      int row = mw + (r & 3) + 8*(r >> 2) + 4*lh;
      Sf[row][col] = ag[r] + h[(tokbase + row)*64 + col] + bs;
    }
  }
  __syncthreads();                       // B_c

  int rrow = tid >> 2, seg = (tid & 3) * 16;   // rrow 0..127
  float h2r[16];
  {
    float vb[16]; float s1 = 0.f;
#pragma unroll
    for (int j4 = 0; j4 < 4; j4++){
      float4 v = *(const float4*)&Sf[rrow][seg + j4*4];
      vb[j4*4+0] = v.x; vb[j4*4+1] = v.y; vb[j4*4+2] = v.z; vb[j4*4+3] = v.w;
      s1 += v.x + v.y + v.z + v.w;
    }
    s1 += __shfl_xor(s1, 1, 64); s1 += __shfl_xor(s1, 2, 64);
    float m = s1 * (1.f/64.f);
    float s2 = 0.f;
#pragma unroll
    for (int j = 0; j < 16; j++){ vb[j] -= m; s2 += vb[j]*vb[j]; }
    s2 += __shfl_xor(s2, 1, 64); s2 += __shfl_xor(s2, 2, 64);
    float rstd = rsqrtf(s2 * (1.f/64.f) + 1e-5f);
    ushort_t tmp[16];
#pragma unroll
    for (int j4 = 0; j4 < 4; j4++){
      float4 gv = *(const float4*)&g_g[seg + j4*4];
      float4 bv = *(const float4*)&b_g[seg + j4*4];
      h2r[j4*4+0] = vb[j4*4+0]*rstd*gv.x + bv.x;
      h2r[j4*4+1] = vb[j4*4+1]*rstd*gv.y + bv.y;
      h2r[j4*4+2] = vb[j4*4+2]*rstd*gv.z + bv.z;
      h2r[j4*4+3] = vb[j4*4+3]*rstd*gv.w + bv.w;
    }
#pragma unroll
    for (int j = 0; j < 16; j++) tmp[j] = f2us(h2r[j]);
    *(uint4*)&RX[rrow][seg]     = *(uint4*)&tmp[0];   // RX readers done at B_b
    *(uint4*)&RX[rrow][seg + 8] = *(uint4*)&tmp[8];
  }
  __syncthreads();                       // B_d (h2 visible; Sf reads drained)

  // ---- P4: FFN (8 waves = 4 m-tiles x 2 col-groups) ----
  int mw1 = (w & 3) * 32, nA = (w >> 2) * 32;
  int mw2 = (w & 3) * 32, dw = (w >> 2) * 32;
  accv16 accO = {};
#pragma unroll
  for (int f0 = 0; f0 < F_; f0 += 128){
    if (f0) __syncthreads();
    accv16 accA = {}, accB = {};
#pragma unroll
    for (int kk = 0; kk < 64; kk += 16){
      frag8 af  = *(const frag8*)&RX[mw1 + l31][kk + lh*8];
      frag8 b0  = *(const frag8*)&W1t[(size_t)(f0 + nA + l31)*64 + kk + lh*8];
      frag8 b1f = *(const frag8*)&W1t[(size_t)(f0 + nA + 64 + l31)*64 + kk + lh*8];
      accA = __builtin_amdgcn_mfma_f32_32x32x16_bf16(af, b0,  accA, 0, 0, 0);
      accB = __builtin_amdgcn_mfma_f32_32x32x16_bf16(af, b1f, accB, 0, 0, 0);
    }
    {
      float bA = b1[f0 + nA + l31];
      float bB = b1[f0 + nA + 64 + l31];
#pragma unroll
      for (int r = 0; r < 16; r++){
        int row = mw1 + (r & 3) + 8*(r >> 2) + 4*lh;
        Uc[row][nA + l31]      = f2us(gelu_f(accA[r] + bA));
        Uc[row][nA + 64 + l31] = f2us(gelu_f(accB[r] + bB));
      }
    }
    __syncthreads();
#pragma unroll
    for (int kk = 0; kk < 128; kk += 16){
      frag8 af = *(const frag8*)&Uc[mw2 + l31][kk + lh*8];
      frag8 bf = *(const frag8*)&W2t[(size_t)(dw + l31)*256 + f0 + kk + lh*8];
      accO = __builtin_amdgcn_mfma_f32_32x32x16_bf16(af, bf, accO, 0, 0, 0);
    }
  }
  __syncthreads();
  {
    float b2v = b2[dw + l31];
#pragma unroll
    for (int r = 0; r < 16; r++){
      int row = mw2 + (r & 3) + 8*(r >> 2) + 4*lh;
      Os[row][dw + l31] = accO[r] + b2v;
    }
  }
  __syncthreads();

  {
    float vb[16]; float s1 = 0.f;
#pragma unroll
    for (int j4 = 0; j4 < 4; j4++){
      float4 v = *(const float4*)&Os[rrow][seg + j4*4];
      vb[j4*4+0] = v.x + h2r[j4*4+0];
      vb[j4*4+1] = v.y + h2r[j4*4+1];
      vb[j4*4+2] = v.z + h2r[j4*4+2];
      vb[j4*4+3] = v.w + h2r[j4*4+3];
      s1 += vb[j4*4+0] + vb[j4*4+1] + vb[j4*4+2] + vb[j4*4+3];
    }
    s1 += __shfl_xor(s1, 1, 64); s1 += __shfl_xor(s1, 2, 64);
    float m = s1 * (1.f/64.f);
    float s2 = 0.f;
#pragma unroll
    for (int j = 0; j < 16; j++){ vb[j] -= m; s2 += vb[j]*vb[j]; }
    s2 += __shfl_xor(s2, 1, 64); s2 += __shfl_xor(s2, 2, 64);
    float rstd = rsqrtf(s2 * (1.f/64.f) + 1e-5f);
#pragma unroll
    for (int j4 = 0; j4 < 4; j4++){
      float4 gv = *(const float4*)&g_f[seg + j4*4];
      float4 bv = *(const float4*)&b_f[seg + j4*4];
      float4 st;
      st.x = vb[j4*4+0]*rstd*gv.x + bv.x;
      st.y = vb[j4*4+1]*rstd*gv.y + bv.y;
      st.z = vb[j4*4+2]*rstd*gv.z + bv.z;
      st.w = vb[j4*4+3]*rstd*gv.w + bv.w;
      *(float4*)&h[(tokbase + rrow)*64 + seg + j4*4] = st;
    }
  }
}

extern "C" void kernel_launch(void* const* d_in, const int* in_sizes, int n_in,
                              void* d_out, int out_size, void* d_ws, size_t ws_size,
                              hipStream_t stream)
{
  const float* x   = (const float*)d_in[0];
  const float* adj = (const float*)d_in[1];
  const float* Wq  = (const float*)d_in[2];
  const float* bq  = (const float*)d_in[3];
  const float* Wk  = (const float*)d_in[4];
  const float* bk  = (const float*)d_in[5];
  const float* Wv  = (const float*)d_in[6];
  const float* bv  = (const float*)d_in[7];
  const float* Wo  = (const float*)d_in[8];
  const float* bo  = (const float*)d_in[9];
  const float* gcW = (const float*)d_in[10];
  const float* gcb = (const float*)d_in[11];
  const float* W1  = (const float*)d_in[12];
  const float* b1  = (const float*)d_in[13];
  const float* W2  = (const float*)d_in[14];
  const float* b2  = (const float*)d_in[15];
  const float* g_t = (const float*)d_in[16];
  const float* b_t = (const float*)d_in[17];
  const float* g_g = (const float*)d_in[18];
  const float* b_g = (const float*)d_in[19];
  const float* g_f = (const float*)d_in[20];
  const float* b_f = (const float*)d_in[21];

  // ws (~28 MB): dinv 2KB | Ahat/AhatT/Ahat2 3x512KB | hT 25.2MB
  //              | W1t/W2t 64KB | Wqt..Wot 32KB | gWt 24KB
  const size_t MD = (size_t)B_*T_*N_*D_;
  const size_t NN = (size_t)N_*N_;
  float* dinv = (float*)d_ws;
  ushort_t* AhatB  = (ushort_t*)(dinv + 512);
  ushort_t* AhatBT = AhatB + NN;
  ushort_t* AhatB2 = AhatBT + NN;
  ushort_t* hT  = AhatB2 + NN;
  ushort_t* W1t = hT + MD;
  ushort_t* W2t = W1t + 256*64;
  ushort_t* Wqt = W2t + 64*256;
  ushort_t* Wkt = Wqt + 4096;
  ushort_t* Wvt = Wkt + 4096;
  ushort_t* Wot = Wvt + 4096;
  ushort_t* gWt = Wot + 4096;
  float* h = (float*)d_out;

  k_dinv<<<N_, 64, 0, stream>>>(adj, dinv);
  k_ahat<<<(N_*N_)/256, 256, 0, stream>>>(adj, dinv, AhatB, AhatBT);
  k_wprep<<<64, 256, 0, stream>>>(W1, W2, Wq, Wk, Wv, Wo, gcW,
                                  W1t, W2t, Wqt, Wkt, Wvt, Wot, gWt);
  k_ah2<<<dim3(8, 8), 256, 0, stream>>>(AhatB, AhatBT, AhatB2);
  k_attn_m<<<B_*N_/2, 256, 0, stream>>>(x, Wqt,bq, Wkt,bk, Wvt,bv, Wot,bo, g_t,b_t, h);
  k_hT<<<B_*T_*8, 256, 0, stream>>>(h, hT);
  k_gcffn<<<(N_/128) * B_ * T_, 512, 0, stream>>>(AhatB, AhatB2, hT, gWt,
                                                  gcb, g_g, b_g,
                                                  W1t, W2t, b1, b2, g_f, b_f, h);
}

// Round 14
// 332.399 us; speedup vs baseline: 1.0761x; 1.0761x over previous
//
#include <hip/hip_runtime.h>
#include <hip/hip_bf16.h>
#include <math.h>

typedef __hip_bfloat16 bf16;
typedef unsigned short ushort_t;

__device__ __forceinline__ float us2f(ushort_t u){
  union { unsigned u; float f; } v; v.u = ((unsigned)u) << 16; return v.f;
}
// native RNE f32->bf16
__device__ __forceinline__ ushort_t f2us(float f){
  union { __bf16 b; ushort_t u; } v; v.b = (__bf16)f; return v.u;
}

// tanh-form GELU == x * sigmoid(2c(x + 0.044715 x^3)); branch-free, NaN-free.
__device__ __forceinline__ float gelu_f(float x){
  float y = x * fmaf(0.0356774081f, x*x, 0.7978845608f);
  float e = __expf(-2.0f*y);
  return x * __builtin_amdgcn_rcpf(1.0f + e);
}

#define B_ 16
#define T_ 24
#define N_ 512
#define D_ 64
#define F_ 256

typedef __attribute__((ext_vector_type(8)))  short  frag8;
typedef __attribute__((ext_vector_type(16))) float  accv16;

__device__ __forceinline__ float wave_sum(float v){
#pragma unroll
  for (int off = 32; off > 0; off >>= 1) v += __shfl_xor(v, off, 64);
  return v;
}

// ---------- degree^-1/2 ----------
__global__ __launch_bounds__(64) void k_dinv(const float* __restrict__ adj,
                                             float* __restrict__ dinv){
  int m = blockIdx.x;
  float s = 0.f;
  for (int n = threadIdx.x; n < N_; n += 64) s += adj[m*N_ + n];
  s = wave_sum(s);
  if (threadIdx.x == 0){
    float deg = s + 1.0f;
    dinv[m] = rsqrtf(fmaxf(deg, 1e-12f));
  }
}

// ---------- Ahat (bf16) + AhatT ----------
__global__ __launch_bounds__(256) void k_ahat(const float* __restrict__ adj,
                                              const float* __restrict__ dinv,
                                              ushort_t* __restrict__ AhatB,
                                              ushort_t* __restrict__ AhatBT){
  int idx = blockIdx.x*256 + threadIdx.x;
  int m = idx >> 9, n = idx & (N_-1);
  float a = adj[idx] + (m == n ? 1.f : 0.f);
  ushort_t v = f2us(dinv[m]*a*dinv[n]);
  AhatB[idx] = v;
  AhatBT[n*N_ + m] = v;
}

// ---------- Ahat^2 = Ahat @ Ahat ----------
__global__ __launch_bounds__(256, 4) void k_ah2(
    const ushort_t* __restrict__ A1,
    const ushort_t* __restrict__ A1T,
    ushort_t* __restrict__ A2)
{
  __shared__ __align__(16) ushort_t Ab[64][72];
  __shared__ __align__(16) ushort_t Bb[64][72];
  __shared__ __align__(16) ushort_t Yt[64][72];
  int tid  = threadIdx.x;
  int lane = tid & 63, w = tid >> 6;
  int mw = (w >> 1) * 32, nw = (w & 1) * 32;
  int l31 = lane & 31, lh = lane >> 5;
  int m0 = blockIdx.x * 64, n0 = blockIdx.y * 64;
  int ar = tid >> 3, ac8 = (tid & 7) * 8;

  accv16 acc = {};
  for (int k0 = 0; k0 < N_; k0 += 64){
#pragma unroll
    for (int g = 0; g < 2; g++){
      int rr = ar + g*32;
      *(uint4*)&Ab[rr][ac8] = *(const uint4*)&A1 [(size_t)(m0 + rr)*N_ + k0 + ac8];
      *(uint4*)&Bb[rr][ac8] = *(const uint4*)&A1T[(size_t)(n0 + rr)*N_ + k0 + ac8];
    }
    __syncthreads();
#pragma unroll
    for (int kk = 0; kk < 64; kk += 16){
      frag8 af = *(const frag8*)&Ab[mw + l31][kk + lh*8];
      frag8 bf = *(const frag8*)&Bb[nw + l31][kk + lh*8];
      acc = __builtin_amdgcn_mfma_f32_32x32x16_bf16(af, bf, acc, 0, 0, 0);
    }
    __syncthreads();
  }
#pragma unroll
  for (int r = 0; r < 16; r++){
    int row = mw + (r & 3) + 8*(r >> 2) + 4*lh;
    Yt[row][nw + l31] = f2us(acc[r]);
  }
  __syncthreads();
#pragma unroll
  for (int g = 0; g < 2; g++){
    int rr = ar + g*32;
    *(uint4*)&A2[(size_t)(m0 + rr)*N_ + n0 + ac8] = *(const uint4*)&Yt[rr][ac8];
  }
}

// ---------- pre-transpose weights to bf16 B-operand layout [dout][e] ----------
__global__ __launch_bounds__(256) void k_wprep(
    const float* __restrict__ W1, const float* __restrict__ W2,
    const float* __restrict__ Wq, const float* __restrict__ Wk,
    const float* __restrict__ Wv, const float* __restrict__ Wo,
    const float* __restrict__ gcW,
    ushort_t* __restrict__ W1t, ushort_t* __restrict__ W2t,
    ushort_t* __restrict__ Wqt, ushort_t* __restrict__ Wkt,
    ushort_t* __restrict__ Wvt, ushort_t* __restrict__ Wot,
    ushort_t* __restrict__ gWt){
  int o = blockIdx.x*256 + threadIdx.x;   // 0..16383
  int f = o >> 6, e = o & 63;
  W1t[o] = f2us(W1[e*256 + f]);
  int d = o >> 8, e2 = o & 255;
  W2t[o] = f2us(W2[e2*64 + d]);
  if (o < 4096){
    int dd = o >> 6, ee = o & 63;
    Wqt[o] = f2us(Wq[ee*64 + dd]);
    Wkt[o] = f2us(Wk[ee*64 + dd]);
    Wvt[o] = f2us(Wv[ee*64 + dd]);
    Wot[o] = f2us(Wo[ee*64 + dd]);
    gWt[o]        = f2us(gcW[       ee*64 + dd]);   // k=0
    gWt[4096 + o] = f2us(gcW[4096 + ee*64 + dd]);   // k=1
    gWt[8192 + o] = f2us(gcW[8192 + ee*64 + dd]);   // k=2
  }
}

// ---------- attention: 2 nodes (48 tokens) per block ----------
// r14: bounds (256,5) -- LDS 28928 admits 5 blocks/CU; VGPR budget 102 vs
// ~60-68 used, so no regalloc squeeze possible (r6's spill was cffn-only).
__global__ __launch_bounds__(256, 5) void k_attn_m(
    const float* __restrict__ x,
    const ushort_t* __restrict__ Wqt, const float* __restrict__ bq,
    const ushort_t* __restrict__ Wkt, const float* __restrict__ bk,
    const ushort_t* __restrict__ Wvt, const float* __restrict__ bv,
    const ushort_t* __restrict__ Wot, const float* __restrict__ bo,
    const float* __restrict__ g_t, const float* __restrict__ b_t,
    float* __restrict__ h1)
{
  __shared__ __align__(16) char smem[28928];
  ushort_t (*xsA)[72] = (ushort_t(*)[72]) smem;                 // [48][72]
  ushort_t (*qs)[72]  = (ushort_t(*)[72])(smem + 6912);         // [48][72]
  ushort_t (*ks)[72]  = (ushort_t(*)[72])(smem + 13824);        // [48][72]
  float    (*Os)[68]  = (float(*)[68])   (smem + 6912);         // [48][68] alias (13056B)
  ushort_t *vsT       = (ushort_t*)(smem + 20736);              // [128][32], swizzled

  int tid = threadIdx.x;
  int lane = tid & 63, w = tid >> 6;
  int l31 = lane & 31, lh = lane >> 5;
  int mt = (w >> 1) * 32, nt = (w & 1) * 32;
  int b = blockIdx.x >> 8;
  int n0 = (blockIdx.x & 255) * 2;

  {
    uint4 z4 = {0,0,0,0};
#pragma unroll
    for (int i = 0; i < 2; i++)
      *(uint4*)(smem + 20736 + (tid + i*256)*16) = z4;
  }
#pragma unroll
  for (int i = 0; i < 3; i++){
    int idx = tid + i*256;
    int row = idx >> 4, d4 = (idx & 15) * 4;
    int node = row >= 24;
    int t = row - node*24;
    const float4 v = *(const float4*)&x[(((size_t)b*T_ + t)*N_ + n0 + node)*D_ + d4];
    ushort_t tmp[4] = { f2us(v.x), f2us(v.y), f2us(v.z), f2us(v.w) };
    *(unsigned long long*)&xsA[row][d4] = *(unsigned long long*)tmp;
  }
  __syncthreads();

#pragma unroll
  for (int pj = 0; pj < 3; pj++){
    const ushort_t* Wp = (pj==0 ? Wqt : pj==1 ? Wkt : Wvt);
    accv16 a = {};
#pragma unroll
    for (int kk = 0; kk < 64; kk += 16){
      frag8 af = *(const frag8*)&xsA[mt + l31][kk + lh*8];
      frag8 bf = *(const frag8*)&Wp[(size_t)(nt + l31)*64 + kk + lh*8];
      a = __builtin_amdgcn_mfma_f32_32x32x16_bf16(af, bf, a, 0, 0, 0);
    }
    float bias = (pj==0 ? bq : pj==1 ? bk : bv)[nt + l31];
    if (pj < 2){
      ushort_t (*dst)[72] = (pj==0 ? qs : ks);
#pragma unroll
      for (int r = 0; r < 16; r++){
        int row = mt + (r & 3) + 8*(r >> 2) + 4*lh;
        if (row < 48) dst[row][nt + l31] = f2us(a[r] + bias);
      }
    } else {
      int cl = nt + l31;                  // 0..63 = head*16 + d_local
#pragma unroll
      for (int r = 0; r < 16; r++){
        int row = mt + (r & 3) + 8*(r >> 2) + 4*lh;
        if (row < 48){
          int node = (row >= 24);
          int t2 = row - node*24;
          int Rr = node*64 + cl;
          vsT[Rr*32 + (((t2 >> 3) ^ ((Rr >> 1) & 3)) << 3) + (t2 & 7)] = f2us(a[r] + bias);
        }
      }
    }
  }
  __syncthreads();

  int vs_s = (l31 >> 1) & 3;
#pragma unroll
  for (int gi = 0; gi < 2; gi++){
    int g = w*2 + gi;
    int node = g >> 2, hh = g & 3;
    accv16 s = {};
    frag8 kf = *(const frag8*)&ks[node*24 + l31][hh*16 + lh*8];
    frag8 qf = *(const frag8*)&qs[node*24 + l31][hh*16 + lh*8];
    s = __builtin_amdgcn_mfma_f32_32x32x16_bf16(kf, qf, s, 0, 0, 0);
    float e[12]; float sm = 0.f;
#pragma unroll
    for (int r = 0; r < 12; r++){ e[r] = __expf(s[r]*0.25f); sm += e[r]; }
    sm += __shfl_xor(sm, 32, 64);
    float rinv = 1.0f / sm;
    union { unsigned long long q; ushort_t u[4]; } a0, a1, a2;
#pragma unroll
    for (int j = 0; j < 4; j++){
      a0.u[j] = f2us(e[j]   * rinv);
      a1.u[j] = f2us(e[4+j] * rinv);
      a2.u[j] = f2us(e[8+j] * rinv);
    }
    unsigned long long send1 = lh ? a0.q : a1.q;
    unsigned long long r1 = __shfl_xor(send1, 32, 64);
    unsigned long long r2 = __shfl_xor(a2.q, 32, 64);
    union { frag8 f; unsigned long long q[2]; } f0, f1;
    f0.q[0] = lh ? r1   : a0.q;
    f0.q[1] = lh ? a1.q : r1;
    f1.q[0] = lh ? 0ULL : a2.q;
    f1.q[1] = lh ? 0ULL : r2;
    int vrow = node*64 + hh*16 + (l31 & 15);
    const ushort_t* vb = &vsT[vrow*32];
    frag8 bf0 = *(const frag8*)&vb[((0 + lh) ^ vs_s) << 3];
    frag8 bf1 = *(const frag8*)&vb[((2 + lh) ^ vs_s) << 3];
    accv16 acc = {};
    acc = __builtin_amdgcn_mfma_f32_32x32x16_bf16(f0.f, bf0, acc, 0, 0, 0);
    acc = __builtin_amdgcn_mfma_f32_32x32x16_bf16(f1.f, bf1, acc, 0, 0, 0);
    if (l31 < 16){
#pragma unroll
      for (int r = 0; r < 12; r++){
        int row = (r & 3) + 8*(r >> 2) + 4*lh;
        xsA[node*24 + row][hh*16 + l31] = f2us(acc[r]);
      }
    }
  }
  __syncthreads();

  accv16 ao = {};
#pragma unroll
  for (int kk = 0; kk < 64; kk += 16){
    frag8 af = *(const frag8*)&xsA[mt + l31][kk + lh*8];
    frag8 bf = *(const frag8*)&Wot[(size_t)(nt + l31)*64 + kk + lh*8];
    ao = __builtin_amdgcn_mfma_f32_32x32x16_bf16(af, bf, ao, 0, 0, 0);
  }
  {
    float bov = bo[nt + l31];
#pragma unroll
    for (int r = 0; r < 16; r++){
      int row = mt + (r & 3) + 8*(r >> 2) + 4*lh;
      if (row < 48) Os[row][nt + l31] = ao[r] + bov;
    }
  }
  __syncthreads();

  // ---- LN tail: 4 lanes per row, fp32 x re-read, float4 I/O ----
  {
    int rrow = tid >> 2, seg = (tid & 3) * 16;
    if (rrow < 48){
      int node = rrow >= 24;
      int t = rrow - node*24;
      size_t gbase = (((size_t)b*T_ + t)*N_ + n0 + node)*D_;
      float vb[16]; float s1 = 0.f;
#pragma unroll
      for (int j4 = 0; j4 < 4; j4++){
        float4 xo = *(const float4*)&x[gbase + seg + j4*4];
        float4 ov = *(const float4*)&Os[rrow][seg + j4*4];
        vb[j4*4+0] = ov.x + xo.x;
        vb[j4*4+1] = ov.y + xo.y;
        vb[j4*4+2] = ov.z + xo.z;
        vb[j4*4+3] = ov.w + xo.w;
        s1 += vb[j4*4+0] + vb[j4*4+1] + vb[j4*4+2] + vb[j4*4+3];
      }
      s1 += __shfl_xor(s1, 1, 64); s1 += __shfl_xor(s1, 2, 64);
      float m = s1 * (1.f/64.f);
      float s2 = 0.f;
#pragma unroll
      for (int j = 0; j < 16; j++){ vb[j] -= m; s2 += vb[j]*vb[j]; }
      s2 += __shfl_xor(s2, 1, 64); s2 += __shfl_xor(s2, 2, 64);
      float rstd = rsqrtf(s2 * (1.f/64.f) + 1e-5f);
#pragma unroll
      for (int j4 = 0; j4 < 4; j4++){
        float4 gv = *(const float4*)&g_t[seg + j4*4];
        float4 bv = *(const float4*)&b_t[seg + j4*4];
        float4 st;
        st.x = vb[j4*4+0]*rstd*gv.x + bv.x;
        st.y = vb[j4*4+1]*rstd*gv.y + bv.y;
        st.z = vb[j4*4+2]*rstd*gv.z + bv.z;
        st.w = vb[j4*4+3]*rstd*gv.w + bv.w;
        *(float4*)&h1[gbase + seg + j4*4] = st;
      }
    }
  }
}

// ---------- hT = transpose(h) per (b,t) slice ----------
__global__ __launch_bounds__(256, 8) void k_hT(const float* __restrict__ h,
                                               ushort_t* __restrict__ hT){
  __shared__ __align__(16) ushort_t tb[64][76];
  int tid = threadIdx.x;
  int n0 = (blockIdx.x & 7) * 64;
  size_t bt = blockIdx.x >> 3;
  const float* src = h + (bt*N_ + n0)*D_;
#pragma unroll
  for (int i = 0; i < 4; i++){
    int q = tid + i*256;
    int row = q >> 4, d4 = (q & 15)*4;
    float4 v = *(const float4*)&src[(size_t)q*4];
    ushort_t tmp[4] = { f2us(v.x), f2us(v.y), f2us(v.z), f2us(v.w) };
    *(unsigned long long*)&tb[row][d4] = *(unsigned long long*)tmp;
  }
  __syncthreads();
  int d = tid >> 2, nseg = (tid & 3)*16;
  ushort_t tmp[16];
#pragma unroll
  for (int j = 0; j < 16; j++){
    int jj = (j + ((d & 7) << 1)) & 15;
    tmp[jj] = tb[nseg + jj][d];
  }
  ushort_t* dst = hT + (bt*D_ + d)*N_ + n0 + nseg;
  *(uint4*)&dst[0] = *(uint4*)&tmp[0];
  *(uint4*)&dst[8] = *(uint4*)&tmp[8];
}

// ---------- fused gconv + comb + FFN (exact r10 configuration) ----------
// BK=64, 8-thread/row uint4 staging, [.][72] strides (0 bank conflicts),
// bounds (256,4), LDS 27648B. Proven 124 us; 4 perturbations all regressed.
__global__ __launch_bounds__(256, 4) void k_gcffn(
    const ushort_t* __restrict__ A1,
    const ushort_t* __restrict__ A2,
    const ushort_t* __restrict__ XT,
    const ushort_t* __restrict__ gWt,   // [3][64][64] bf16 B-layout
    const float* __restrict__ gcb,
    const float* __restrict__ g_g, const float* __restrict__ b_g,
    const ushort_t* __restrict__ W1t, const ushort_t* __restrict__ W2t,
    const float* __restrict__ b1, const float* __restrict__ b2,
    const float* __restrict__ g_f, const float* __restrict__ b_f,
    float* __restrict__ h)
{
  __shared__ __align__(16) char smem[27648];
  ushort_t (*R0)[72]  = (ushort_t(*)[72]) smem;            // A1 tile / Y2 / (Sf,Uc lo)
  ushort_t (*R1)[72]  = (ushort_t(*)[72])(smem +  9216);   // A2 tile / Y1 / (Sf,Uc hi)
  ushort_t (*hsA)[72] = (ushort_t(*)[72])(smem + 18432);   // X tile / h1,h2 bf16
  float    (*Sf)[68]  = (float(*)[68])    smem;            // [64][68] f32
  ushort_t (*Uc)[136] = (ushort_t(*)[136])smem;            // [64][136] bf16
  float    (*Os)[68]  = (float(*)[68])    smem;

  int tid = threadIdx.x;
  int lane = tid & 63, w = tid >> 6;
  int l31 = lane & 31, lh = lane >> 5;
  int mw = (w >> 1) * 32, nw = (w & 1) * 32;
  // XCD-aware decode: bid%8 pins XCD; slice = (bid>>6)*8 + bid%8; m = (bid>>3)&7
  int bid = blockIdx.x;
  int m0 = ((bid >> 3) & 7) * 64;
  size_t bt = (size_t)((bid >> 6) * 8 + (bid & 7));
  const ushort_t* Xg = XT + bt * (N_ * D_);
  size_t tokbase = bt * N_ + m0;
  int ar = tid >> 3, ac8 = (tid & 7) * 8;

  // ---- P1: dual-hop K-loop ----
  accv16 acc1 = {}, acc2 = {};
  for (int k0 = 0; k0 < N_; k0 += 64){
#pragma unroll
    for (int g = 0; g < 2; g++){
      int rr = ar + g*32;
      *(uint4*)&R0 [rr][ac8] = *(const uint4*)&A1[(size_t)(m0 + rr)*N_ + k0 + ac8];
      *(uint4*)&R1 [rr][ac8] = *(const uint4*)&A2[(size_t)(m0 + rr)*N_ + k0 + ac8];
      *(uint4*)&hsA[rr][ac8] = *(const uint4*)&Xg[(size_t)rr*N_ + k0 + ac8];
    }
    __syncthreads();
#pragma unroll
    for (int kk = 0; kk < 64; kk += 16){
      frag8 bf  = *(const frag8*)&hsA[nw + l31][kk + lh*8];
      frag8 af1 = *(const frag8*)&R0 [mw + l31][kk + lh*8];
      frag8 af2 = *(const frag8*)&R1 [mw + l31][kk + lh*8];
      acc1 = __builtin_amdgcn_mfma_f32_32x32x16_bf16(af1, bf, acc1, 0, 0, 0);
      acc2 = __builtin_amdgcn_mfma_f32_32x32x16_bf16(af2, bf, acc2, 0, 0, 0);
    }
    __syncthreads();
  }

  // ---- P2: Y writes + h1 tile stage; 3-term g-sum ----
#pragma unroll
  for (int r = 0; r < 16; r++){
    int row = mw + (r & 3) + 8*(r >> 2) + 4*lh;
    R1[row][nw + l31] = f2us(acc1[r]);   // Y1
    R0[row][nw + l31] = f2us(acc2[r]);   // Y2
  }
#pragma unroll
  for (int i = 0; i < 4; i++){
    int q = tid + i*256;                 // float4 idx over 64x64 tile
    int row = q >> 4, d4 = (q & 15) * 4;
    float4 v = *(const float4*)&h[tokbase*64 + (size_t)q*4];
    ushort_t tmp[4] = { f2us(v.x), f2us(v.y), f2us(v.z), f2us(v.w) };
    *(unsigned long long*)&hsA[row][d4] = *(unsigned long long*)tmp;
  }
  __syncthreads();                       // B_a

  accv16 ag = {};
#pragma unroll
  for (int kk = 0; kk < 64; kk += 16){
    frag8 a0f = *(const frag8*)&hsA[mw + l31][kk + lh*8];
    frag8 b0f = *(const frag8*)&gWt[(size_t)(nw + l31)*64 + kk + lh*8];
    ag = __builtin_amdgcn_mfma_f32_32x32x16_bf16(a0f, b0f, ag, 0, 0, 0);
  }
#pragma unroll
  for (int kk = 0; kk < 64; kk += 16){
    frag8 a1f = *(const frag8*)&R1[mw + l31][kk + lh*8];
    frag8 b1f = *(const frag8*)&gWt[4096 + (size_t)(nw + l31)*64 + kk + lh*8];
    ag = __builtin_amdgcn_mfma_f32_32x32x16_bf16(a1f, b1f, ag, 0, 0, 0);
  }
#pragma unroll
  for (int kk = 0; kk < 64; kk += 16){
    frag8 a2f = *(const frag8*)&R0[mw + l31][kk + lh*8];
    frag8 b2f = *(const frag8*)&gWt[8192 + (size_t)(nw + l31)*64 + kk + lh*8];
    ag = __builtin_amdgcn_mfma_f32_32x32x16_bf16(a2f, b2f, ag, 0, 0, 0);
  }
  __syncthreads();                       // B_b: drain R0/R1/hsA reads

  // ---- P3: S = ag + h1(fp32) + bias -> Sf; mid-LN ----
  {
    int col = nw + l31;
    float bs = gcb[col] + gcb[64 + col] + gcb[128 + col];
#pragma unroll
    for (int r = 0; r < 16; r++){
      int row = mw + (r & 3) + 8*(r >> 2) + 4*lh;
      Sf[row][col] = ag[r] + h[(tokbase + row)*64 + col] + bs;
    }
  }
  __syncthreads();                       // B_c

  int rrow = tid >> 2, seg = (tid & 3) * 16;
  float h2r[16];
  {
    float vb[16]; float s1 = 0.f;
#pragma unroll
    for (int j4 = 0; j4 < 4; j4++){
      float4 v = *(const float4*)&Sf[rrow][seg + j4*4];
      vb[j4*4+0] = v.x; vb[j4*4+1] = v.y; vb[j4*4+2] = v.z; vb[j4*4+3] = v.w;
      s1 += v.x + v.y + v.z + v.w;
    }
    s1 += __shfl_xor(s1, 1, 64); s1 += __shfl_xor(s1, 2, 64);
    float m = s1 * (1.f/64.f);
    float s2 = 0.f;
#pragma unroll
    for (int j = 0; j < 16; j++){ vb[j] -= m; s2 += vb[j]*vb[j]; }
    s2 += __shfl_xor(s2, 1, 64); s2 += __shfl_xor(s2, 2, 64);
    float rstd = rsqrtf(s2 * (1.f/64.f) + 1e-5f);
    ushort_t tmp[16];
#pragma unroll
    for (int j4 = 0; j4 < 4; j4++){
      float4 gv = *(const float4*)&g_g[seg + j4*4];
      float4 bv = *(const float4*)&b_g[seg + j4*4];
      h2r[j4*4+0] = vb[j4*4+0]*rstd*gv.x + bv.x;
      h2r[j4*4+1] = vb[j4*4+1]*rstd*gv.y + bv.y;
      h2r[j4*4+2] = vb[j4*4+2]*rstd*gv.z + bv.z;
      h2r[j4*4+3] = vb[j4*4+3]*rstd*gv.w + bv.w;
    }
#pragma unroll
    for (int j = 0; j < 16; j++) tmp[j] = f2us(h2r[j]);
    *(uint4*)&hsA[rrow][seg]     = *(uint4*)&tmp[0];   // hsA readers done at B_b
    *(uint4*)&hsA[rrow][seg + 8] = *(uint4*)&tmp[8];
  }
  __syncthreads();                       // B_d (h2 visible; Sf reads drained)

  // ---- P4: FFN ----
  int mw1 = (w & 1) * 32, nA = (w >> 1) * 32;
  int mw2 = (w >> 1) * 32, dw = (w & 1) * 32;
  accv16 accO = {};
#pragma unroll
  for (int f0 = 0; f0 < F_; f0 += 128){
    if (f0) __syncthreads();
    accv16 accA = {}, accB = {};
#pragma unroll
    for (int kk = 0; kk < 64; kk += 16){
      frag8 af  = *(const frag8*)&hsA[mw1 + l31][kk + lh*8];
      frag8 b0  = *(const frag8*)&W1t[(size_t)(f0 + nA + l31)*64 + kk + lh*8];
      frag8 b1f = *(const frag8*)&W1t[(size_t)(f0 + nA + 64 + l31)*64 + kk + lh*8];
      accA = __builtin_amdgcn_mfma_f32_32x32x16_bf16(af, b0,  accA, 0, 0, 0);
      accB = __builtin_amdgcn_mfma_f32_32x32x16_bf16(af, b1f, accB, 0, 0, 0);
    }
    {
      float bA = b1[f0 + nA + l31];
      float bB = b1[f0 + nA + 64 + l31];
#pragma unroll
      for (int r = 0; r < 16; r++){
        int row = mw1 + (r & 3) + 8*(r >> 2) + 4*lh;
        Uc[row][nA + l31]      = f2us(gelu_f(accA[r] + bA));
        Uc[row][nA + 64 + l31] = f2us(gelu_f(accB[r] + bB));
      }
    }
    __syncthreads();
#pragma unroll
    for (int kk = 0; kk < 128; kk += 16){
      frag8 af = *(const frag8*)&Uc[mw2 + l31][kk + lh*8];
      frag8 bf = *(const frag8*)&W2t[(size_t)(dw + l31)*256 + f0 + kk + lh*8];
      accO = __builtin_amdgcn_mfma_f32_32x32x16_bf16(af, bf, accO, 0, 0, 0);
    }
  }
  __syncthreads();
  {
    float b2v = b2[dw + l31];
#pragma unroll
    for (int r = 0; r < 16; r++){
      int row = mw2 + (r & 3) + 8*(r >> 2) + 4*lh;
      Os[row][dw + l31] = accO[r] + b2v;
    }
  }
  __syncthreads();

  {
    float vb[16]; float s1 = 0.f;
#pragma unroll
    for (int j4 = 0; j4 < 4; j4++){
      float4 v = *(const float4*)&Os[rrow][seg + j4*4];
      vb[j4*4+0] = v.x + h2r[j4*4+0];
      vb[j4*4+1] = v.y + h2r[j4*4+1];
      vb[j4*4+2] = v.z + h2r[j4*4+2];
      vb[j4*4+3] = v.w + h2r[j4*4+3];
      s1 += vb[j4*4+0] + vb[j4*4+1] + vb[j4*4+2] + vb[j4*4+3];
    }
    s1 += __shfl_xor(s1, 1, 64); s1 += __shfl_xor(s1, 2, 64);
    float m = s1 * (1.f/64.f);
    float s2 = 0.f;
#pragma unroll
    for (int j = 0; j < 16; j++){ vb[j] -= m; s2 += vb[j]*vb[j]; }
    s2 += __shfl_xor(s2, 1, 64); s2 += __shfl_xor(s2, 2, 64);
    float rstd = rsqrtf(s2 * (1.f/64.f) + 1e-5f);
#pragma unroll
    for (int j4 = 0; j4 < 4; j4++){
      float4 gv = *(const float4*)&g_f[seg + j4*4];
      float4 bv = *(const float4*)&b_f[seg + j4*4];
      float4 st;
      st.x = vb[j4*4+0]*rstd*gv.x + bv.x;
      st.y = vb[j4*4+1]*rstd*gv.y + bv.y;
      st.z = vb[j4*4+2]*rstd*gv.z + bv.z;
      st.w = vb[j4*4+3]*rstd*gv.w + bv.w;
      *(float4*)&h[(tokbase + rrow)*64 + seg + j4*4] = st;
    }
  }
}

extern "C" void kernel_launch(void* const* d_in, const int* in_sizes, int n_in,
                              void* d_out, int out_size, void* d_ws, size_t ws_size,
                              hipStream_t stream)
{
  const float* x   = (const float*)d_in[0];
  const float* adj = (const float*)d_in[1];
  const float* Wq  = (const float*)d_in[2];
  const float* bq  = (const float*)d_in[3];
  const float* Wk  = (const float*)d_in[4];
  const float* bk  = (const float*)d_in[5];
  const float* Wv  = (const float*)d_in[6];
  const float* bv  = (const float*)d_in[7];
  const float* Wo  = (const float*)d_in[8];
  const float* bo  = (const float*)d_in[9];
  const float* gcW = (const float*)d_in[10];
  const float* gcb = (const float*)d_in[11];
  const float* W1  = (const float*)d_in[12];
  const float* b1  = (const float*)d_in[13];
  const float* W2  = (const float*)d_in[14];
  const float* b2  = (const float*)d_in[15];
  const float* g_t = (const float*)d_in[16];
  const float* b_t = (const float*)d_in[17];
  const float* g_g = (const float*)d_in[18];
  const float* b_g = (const float*)d_in[19];
  const float* g_f = (const float*)d_in[20];
  const float* b_f = (const float*)d_in[21];

  // ws (~28 MB): dinv 2KB | Ahat/AhatT/Ahat2 3x512KB | hT 25.2MB
  //              | W1t/W2t 64KB | Wqt..Wot 32KB | gWt 24KB
  const size_t MD = (size_t)B_*T_*N_*D_;
  const size_t NN = (size_t)N_*N_;
  float* dinv = (float*)d_ws;
  ushort_t* AhatB  = (ushort_t*)(dinv + 512);
  ushort_t* AhatBT = AhatB + NN;
  ushort_t* AhatB2 = AhatBT + NN;
  ushort_t* hT  = AhatB2 + NN;
  ushort_t* W1t = hT + MD;
  ushort_t* W2t = W1t + 256*64;
  ushort_t* Wqt = W2t + 64*256;
  ushort_t* Wkt = Wqt + 4096;
  ushort_t* Wvt = Wkt + 4096;
  ushort_t* Wot = Wvt + 4096;
  ushort_t* gWt = Wot + 4096;
  float* h = (float*)d_out;

  k_dinv<<<N_, 64, 0, stream>>>(adj, dinv);
  k_ahat<<<(N_*N_)/256, 256, 0, stream>>>(adj, dinv, AhatB, AhatBT);
  k_wprep<<<64, 256, 0, stream>>>(W1, W2, Wq, Wk, Wv, Wo, gcW,
                                  W1t, W2t, Wqt, Wkt, Wvt, Wot, gWt);
  k_ah2<<<dim3(8, 8), 256, 0, stream>>>(AhatB, AhatBT, AhatB2);
  k_attn_m<<<B_*N_/2, 256, 0, stream>>>(x, Wqt,bq, Wkt,bk, Wvt,bv, Wot,bo, g_t,b_t, h);
  k_hT<<<B_*T_*8, 256, 0, stream>>>(h, hT);
  k_gcffn<<<(N_/64) * B_ * T_, 256, 0, stream>>>(AhatB, AhatB2, hT, gWt,
                                                 gcb, g_g, b_g,
                                                 W1t, W2t, b1, b2, g_f, b_f, h);
}